// Round 8
// baseline (103.261 us; speedup 1.0000x reference)
//
#include <hip/hip_runtime.h>

typedef __attribute__((ext_vector_type(4))) float f32x4;

#define NLVL 16

// Per-level constants from the reference's _level_params() (f64 math -> f32).
constexpr float SCALEC[NLVL] = {
    15.0f, 19.15873679831797f, 24.39841683149119f, 31.0f,
    39.31747359663594f, 49.79683366298238f, 63.0f, 79.63494719327189f,
    100.59366732596477f, 127.0f, 160.26989438654376f, 202.18733465192954f,
    255.0f, 321.5397887730875f, 405.3746693038591f, 511.0f
};
constexpr int RESC[NLVL] = {
    16, 21, 26, 32, 41, 51, 64, 81, 102, 128, 162, 204, 256, 323, 407, 512
};
constexpr int OFFC[NLVL] = {
    0, 4096, 13360, 30936, 63704, 132632, 265288, 527432,
    1051720, 1576008, 2100296, 2624584, 3148872, 3673160, 4197448, 4721736
};
// Levels 0..6: lin (incl. corner offsets) < res^3 <= hsize -> mask is a no-op.
// Levels 7..15: hsize == 2^19 -> lin & 0x7FFFF; x-pair (e0,e0+1) wraps when
// e0 == 0x7FFFF -> cndmask fix with the level's entry 0 (uniform s_load).
constexpr int HMASK = 0x7FFFF;

// Issue level L's 4 pair-loads via inline asm (pinned: compiler cannot sink
// them past the consumer, so they genuinely stay in flight).
template<int L>
__device__ __forceinline__ void lvl_issue_asm(float x, float y, float z,
                                              const float* __restrict__ emb,
                                              f32x4& q0, f32x4& q1,
                                              f32x4& q2, f32x4& q3)
{
    constexpr float s  = SCALEC[L];
    constexpr int   r  = RESC[L];
    constexpr int   r2 = RESC[L] * RESC[L];
    constexpr int   off = OFFC[L];

    const float px = x * s, py = y * s, pz = z * s;
    const int lin = (int)floorf(px) + r * (int)floorf(py) + r2 * (int)floorf(pz);
    int i0 = lin, i1 = lin + r, i2 = lin + r2, i3 = lin + r2 + r;
    if constexpr (L >= 7) { i0 &= HMASK; i1 &= HMASK; i2 &= HMASK; i3 &= HMASK; }
    const float* p0 = emb + 2 * (off + i0);
    const float* p1 = emb + 2 * (off + i1);
    const float* p2 = emb + 2 * (off + i2);
    const float* p3 = emb + 2 * (off + i3);
    asm volatile("global_load_dwordx4 %0, %1, off" : "=v"(q0) : "v"(p0));
    asm volatile("global_load_dwordx4 %0, %1, off" : "=v"(q1) : "v"(p1));
    asm volatile("global_load_dwordx4 %0, %1, off" : "=v"(q2) : "v"(p2));
    asm volatile("global_load_dwordx4 %0, %1, off" : "=v"(q3) : "v"(p3));
}

// Finish level L: rare-wrap fix, trilinear weights, reduce to (a0, a1).
template<int L>
__device__ __forceinline__ void lvl_finish(float x, float y, float z,
                                           const float* __restrict__ emb,
                                           f32x4 q0, f32x4 q1,
                                           f32x4 q2, f32x4 q3,
                                           float& a0, float& a1)
{
    constexpr float s  = SCALEC[L];
    constexpr int   r  = RESC[L];
    constexpr int   r2 = RESC[L] * RESC[L];
    constexpr int   off = OFFC[L];

    const float px = x * s, py = y * s, pz = z * s;
    const float tx = px - floorf(px), ty = py - floorf(py), tz = pz - floorf(pz);

    if constexpr (L >= 7) {
        const int lin = (int)floorf(px) + r * (int)floorf(py) + r2 * (int)floorf(pz);
        const int i0 = lin & HMASK, i1 = (lin + r) & HMASK;
        const int i2 = (lin + r2) & HMASK, i3 = (lin + r2 + r) & HMASK;
        const float f0x = emb[2 * off], f0y = emb[2 * off + 1];  // uniform s_load
        q0.z = (i0 == HMASK) ? f0x : q0.z;  q0.w = (i0 == HMASK) ? f0y : q0.w;
        q1.z = (i1 == HMASK) ? f0x : q1.z;  q1.w = (i1 == HMASK) ? f0y : q1.w;
        q2.z = (i2 == HMASK) ? f0x : q2.z;  q2.w = (i2 == HMASK) ? f0y : q2.w;
        q3.z = (i3 == HMASK) ? f0x : q3.z;  q3.w = (i3 == HMASK) ? f0y : q3.w;
    }

    const float wx1 = tx, wx0 = 1.0f - tx;
    const float wy1 = ty, wy0 = 1.0f - ty;
    const float wz1 = tz, wz0 = 1.0f - tz;
    const float w00 = wy0 * wz0, w10 = wy1 * wz0;
    const float w01 = wy0 * wz1, w11 = wy1 * wz1;
    float r0 = 0.0f, r1 = 0.0f;
    r0 = fmaf(w00 * wx0, q0.x, r0); r1 = fmaf(w00 * wx0, q0.y, r1);
    r0 = fmaf(w00 * wx1, q0.z, r0); r1 = fmaf(w00 * wx1, q0.w, r1);
    r0 = fmaf(w10 * wx0, q1.x, r0); r1 = fmaf(w10 * wx0, q1.y, r1);
    r0 = fmaf(w10 * wx1, q1.z, r0); r1 = fmaf(w10 * wx1, q1.w, r1);
    r0 = fmaf(w01 * wx0, q2.x, r0); r1 = fmaf(w01 * wx0, q2.y, r1);
    r0 = fmaf(w01 * wx1, q2.z, r0); r1 = fmaf(w01 * wx1, q2.w, r1);
    r0 = fmaf(w11 * wx0, q3.x, r0); r1 = fmaf(w11 * wx0, q3.y, r1);
    r0 = fmaf(w11 * wx1, q3.z, r0); r1 = fmaf(w11 * wx1, q3.w, r1);
    a0 = r0; a1 = r1;
}

// ---------------- Pass 1: gather-only -----------------------------------
// Flat grid; pair = blockIdx.x & 7 so (with round-robin block->XCD dispatch)
// each XCD serves ONE level-pair: its table slice (lo<=2MB + hi 4MB) is
// mostly L2-resident. 2 points/thread, 16 asm-pinned loads in flight.
template<int G>
__device__ __forceinline__ void enc_pair2(int p0, int p1,
                                          float x0, float y0, float z0,
                                          float x1, float y1, float z1,
                                          const float* __restrict__ emb,
                                          float* __restrict__ ws, int n)
{
    constexpr int LA = G, LB = G + 8;
    f32x4 a0, a1, a2, a3, b0, b1, b2, b3;
    f32x4 c0, c1, c2, c3, d0, d1, d2, d3;
    lvl_issue_asm<LA>(x0, y0, z0, emb, a0, a1, a2, a3);
    lvl_issue_asm<LB>(x0, y0, z0, emb, b0, b1, b2, b3);
    lvl_issue_asm<LA>(x1, y1, z1, emb, c0, c1, c2, c3);
    lvl_issue_asm<LB>(x1, y1, z1, emb, d0, d1, d2, d3);

    float e0, e1;
#define VMWAIT(N) asm volatile("s_waitcnt vmcnt(" #N ")" ::: "memory"); \
                  __builtin_amdgcn_sched_barrier(0);
    VMWAIT(12)
    lvl_finish<LA>(x0, y0, z0, emb, a0, a1, a2, a3, e0, e1);
    ws[(size_t)(2 * LA + 0) * n + p0] = e0;
    ws[(size_t)(2 * LA + 1) * n + p0] = e1;
    VMWAIT(8)
    lvl_finish<LB>(x0, y0, z0, emb, b0, b1, b2, b3, e0, e1);
    ws[(size_t)(2 * LB + 0) * n + p0] = e0;
    ws[(size_t)(2 * LB + 1) * n + p0] = e1;
    VMWAIT(4)
    lvl_finish<LA>(x1, y1, z1, emb, c0, c1, c2, c3, e0, e1);
    ws[(size_t)(2 * LA + 0) * n + p1] = e0;
    ws[(size_t)(2 * LA + 1) * n + p1] = e1;
    VMWAIT(0)
    lvl_finish<LB>(x1, y1, z1, emb, d0, d1, d2, d3, e0, e1);
    ws[(size_t)(2 * LB + 0) * n + p1] = e0;
    ws[(size_t)(2 * LB + 1) * n + p1] = e1;
#undef VMWAIT
}

__global__ __launch_bounds__(256)
void enc_kernel(const float* __restrict__ coords,
                const float* __restrict__ emb,
                float* __restrict__ ws, int n)
{
    const int pair = blockIdx.x & 7;          // XCD-affine level-pair
    const int pblk = blockIdx.x >> 3;
    const int p0 = pblk * 512 + threadIdx.x;
    const int p1 = p0 + 256;
    if (p1 >= n) {
        if (p0 >= n) return;
        // tail: handle p0 only (n % 512 != 0 case; absent for N=262144)
        const float x = (coords[p0 * 3 + 0] + 1.0f) * 0.5f;
        const float y = (coords[p0 * 3 + 1] + 1.0f) * 0.5f;
        const float z = (coords[p0 * 3 + 2] + 1.0f) * 0.5f;
        f32x4 a0, a1, a2, a3, b0, b1, b2, b3;
        float e0, e1;
        switch (pair) {
#define CASE1(G) case G: { \
            lvl_issue_asm<G>(x, y, z, emb, a0, a1, a2, a3); \
            lvl_issue_asm<G + 8>(x, y, z, emb, b0, b1, b2, b3); \
            asm volatile("s_waitcnt vmcnt(4)" ::: "memory"); \
            __builtin_amdgcn_sched_barrier(0); \
            lvl_finish<G>(x, y, z, emb, a0, a1, a2, a3, e0, e1); \
            ws[(size_t)(2 * G + 0) * n + p0] = e0; \
            ws[(size_t)(2 * G + 1) * n + p0] = e1; \
            asm volatile("s_waitcnt vmcnt(0)" ::: "memory"); \
            __builtin_amdgcn_sched_barrier(0); \
            lvl_finish<G + 8>(x, y, z, emb, b0, b1, b2, b3, e0, e1); \
            ws[(size_t)(2 * (G + 8) + 0) * n + p0] = e0; \
            ws[(size_t)(2 * (G + 8) + 1) * n + p0] = e1; } break;
            CASE1(0) CASE1(1) CASE1(2) CASE1(3)
            CASE1(4) CASE1(5) CASE1(6) CASE1(7)
#undef CASE1
        }
        return;
    }

    const float x0 = (coords[p0 * 3 + 0] + 1.0f) * 0.5f;
    const float y0 = (coords[p0 * 3 + 1] + 1.0f) * 0.5f;
    const float z0 = (coords[p0 * 3 + 2] + 1.0f) * 0.5f;
    const float x1 = (coords[p1 * 3 + 0] + 1.0f) * 0.5f;
    const float y1 = (coords[p1 * 3 + 1] + 1.0f) * 0.5f;
    const float z1 = (coords[p1 * 3 + 2] + 1.0f) * 0.5f;

    switch (pair) {   // block-uniform scalar branch, compile-time constants
        case 0: enc_pair2<0>(p0, p1, x0, y0, z0, x1, y1, z1, emb, ws, n); break;
        case 1: enc_pair2<1>(p0, p1, x0, y0, z0, x1, y1, z1, emb, ws, n); break;
        case 2: enc_pair2<2>(p0, p1, x0, y0, z0, x1, y1, z1, emb, ws, n); break;
        case 3: enc_pair2<3>(p0, p1, x0, y0, z0, x1, y1, z1, emb, ws, n); break;
        case 4: enc_pair2<4>(p0, p1, x0, y0, z0, x1, y1, z1, emb, ws, n); break;
        case 5: enc_pair2<5>(p0, p1, x0, y0, z0, x1, y1, z1, emb, ws, n); break;
        case 6: enc_pair2<6>(p0, p1, x0, y0, z0, x1, y1, z1, emb, ws, n); break;
        default: enc_pair2<7>(p0, p1, x0, y0, z0, x1, y1, z1, emb, ws, n); break;
    }
}

// ---------------- Pass 2: MLP only ------------------------------------------
__global__ __launch_bounds__(256)
void mlp_kernel(const float* __restrict__ ws,
                const float* __restrict__ W0, const float* __restrict__ b0,
                const float* __restrict__ W1, const float* __restrict__ b1,
                const float* __restrict__ W2, const float* __restrict__ b2,
                float* __restrict__ out, int n)
{
    const int p = blockIdx.x * 256 + threadIdx.x;
    if (p >= n) return;

    float enc[32];
#pragma unroll
    for (int c = 0; c < 32; ++c) enc[c] = ws[(size_t)c * n + p];  // coalesced

    float h0[32];
#pragma unroll
    for (int j = 0; j < 32; ++j) h0[j] = b0[j];
#pragma unroll
    for (int i = 0; i < 32; ++i) {
        const float e = enc[i];
#pragma unroll
        for (int j = 0; j < 32; ++j) h0[j] = fmaf(e, W0[i * 32 + j], h0[j]);
    }
#pragma unroll
    for (int j = 0; j < 32; ++j) h0[j] = (h0[j] >= 0.0f) ? h0[j] : 0.01f * h0[j];

    float h1[32];
#pragma unroll
    for (int j = 0; j < 32; ++j) h1[j] = b1[j];
#pragma unroll
    for (int i = 0; i < 32; ++i) {
        const float e = h0[i];
#pragma unroll
        for (int j = 0; j < 32; ++j) h1[j] = fmaf(e, W1[i * 32 + j], h1[j]);
    }
#pragma unroll
    for (int j = 0; j < 32; ++j) h1[j] = (h1[j] >= 0.0f) ? h1[j] : 0.01f * h1[j];

    float acc = b2[0];
#pragma unroll
    for (int j = 0; j < 32; ++j) acc = fmaf(h1[j], W2[j], acc);

    out[p] = acc;
}

// ---------------- Fallback: fused single kernel (r3 structure) ---------------
__device__ __forceinline__ void lvl_issue_c(int L_dummy, float, float, float,
                                            const float*, float4&, float4&,
                                            float4&, float4&) {}

template<int L>
__device__ __forceinline__ void lvl_issue(float x, float y, float z,
                                          const float* __restrict__ emb,
                                          float4& q0, float4& q1,
                                          float4& q2, float4& q3)
{
    constexpr float s  = SCALEC[L];
    constexpr int   r  = RESC[L];
    constexpr int   r2 = RESC[L] * RESC[L];
    constexpr int   off = OFFC[L];
    const float px = x * s, py = y * s, pz = z * s;
    const int lin = (int)floorf(px) + r * (int)floorf(py) + r2 * (int)floorf(pz);
    int i0 = lin, i1 = lin + r, i2 = lin + r2, i3 = lin + r2 + r;
    if constexpr (L >= 7) { i0 &= HMASK; i1 &= HMASK; i2 &= HMASK; i3 &= HMASK; }
    __builtin_memcpy(&q0, emb + 2 * (off + i0), 16);
    __builtin_memcpy(&q1, emb + 2 * (off + i1), 16);
    __builtin_memcpy(&q2, emb + 2 * (off + i2), 16);
    __builtin_memcpy(&q3, emb + 2 * (off + i3), 16);
}

template<int L>
__device__ __forceinline__ void fuse_level(float x, float y, float z,
                                           const float* __restrict__ emb,
                                           float4 q0, float4 q1,
                                           float4 q2, float4 q3,
                                           float* __restrict__ h0,
                                           const float* __restrict__ W0)
{
    f32x4 v0 = {q0.x, q0.y, q0.z, q0.w}, v1 = {q1.x, q1.y, q1.z, q1.w};
    f32x4 v2 = {q2.x, q2.y, q2.z, q2.w}, v3 = {q3.x, q3.y, q3.z, q3.w};
    float a0, a1;
    lvl_finish<L>(x, y, z, emb, v0, v1, v2, v3, a0, a1);
#pragma unroll
    for (int j = 0; j < 32; ++j)
        h0[j] = fmaf(a0, W0[(2 * L + 0) * 32 + j], h0[j]);
#pragma unroll
    for (int j = 0; j < 32; ++j)
        h0[j] = fmaf(a1, W0[(2 * L + 1) * 32 + j], h0[j]);
}

__global__ __launch_bounds__(256, 4)
void fused_kernel(const float* __restrict__ coords,
                  const float* __restrict__ emb,
                  const float* __restrict__ W0, const float* __restrict__ b0,
                  const float* __restrict__ W1, const float* __restrict__ b1,
                  const float* __restrict__ W2, const float* __restrict__ b2,
                  float* __restrict__ out, int n)
{
    const int tid = blockIdx.x * blockDim.x + threadIdx.x;
    if (tid >= n) return;
    const float x = (coords[tid * 3 + 0] + 1.0f) * 0.5f;
    const float y = (coords[tid * 3 + 1] + 1.0f) * 0.5f;
    const float z = (coords[tid * 3 + 2] + 1.0f) * 0.5f;

    float h0[32];
#pragma unroll
    for (int j = 0; j < 32; ++j) h0[j] = b0[j];

    float4 a0, a1, a2, a3, b0r, b1r, b2r, b3r;
#define ISS_A(L) lvl_issue<L>(x, y, z, emb, a0, a1, a2, a3);
#define ISS_B(L) lvl_issue<L>(x, y, z, emb, b0r, b1r, b2r, b3r);
#define FUS_A(L) fuse_level<L>(x, y, z, emb, a0, a1, a2, a3, h0, W0);
#define FUS_B(L) fuse_level<L>(x, y, z, emb, b0r, b1r, b2r, b3r, h0, W0);
    ISS_A(0)
    ISS_B(1)  FUS_A(0)
    ISS_A(2)  FUS_B(1)
    ISS_B(3)  FUS_A(2)
    ISS_A(4)  FUS_B(3)
    ISS_B(5)  FUS_A(4)
    ISS_A(6)  FUS_B(5)
    ISS_B(7)  FUS_A(6)
    ISS_A(8)  FUS_B(7)
    ISS_B(9)  FUS_A(8)
    ISS_A(10) FUS_B(9)
    ISS_B(11) FUS_A(10)
    ISS_A(12) FUS_B(11)
    ISS_B(13) FUS_A(12)
    ISS_A(14) FUS_B(13)
    ISS_B(15) FUS_A(14)
    FUS_B(15)
#undef ISS_A
#undef ISS_B
#undef FUS_A
#undef FUS_B

#pragma unroll
    for (int j = 0; j < 32; ++j) h0[j] = (h0[j] >= 0.0f) ? h0[j] : 0.01f * h0[j];
    float h1[32];
#pragma unroll
    for (int j = 0; j < 32; ++j) h1[j] = b1[j];
#pragma unroll
    for (int i = 0; i < 32; ++i) {
        const float e = h0[i];
#pragma unroll
        for (int j = 0; j < 32; ++j) h1[j] = fmaf(e, W1[i * 32 + j], h1[j]);
    }
#pragma unroll
    for (int j = 0; j < 32; ++j) h1[j] = (h1[j] >= 0.0f) ? h1[j] : 0.01f * h1[j];
    float acc = b2[0];
#pragma unroll
    for (int j = 0; j < 32; ++j) acc = fmaf(h1[j], W2[j], acc);
    out[tid] = acc;
}

extern "C" void kernel_launch(void* const* d_in, const int* in_sizes, int n_in,
                              void* d_out, int out_size, void* d_ws, size_t ws_size,
                              hipStream_t stream) {
    const float* coords = (const float*)d_in[0];   // [N,1,3]
    const float* emb    = (const float*)d_in[1];   // [total,1,2]
    const float* W0     = (const float*)d_in[2];
    const float* b0     = (const float*)d_in[3];
    const float* W1     = (const float*)d_in[4];
    const float* b1     = (const float*)d_in[5];
    const float* W2     = (const float*)d_in[6];
    const float* b2     = (const float*)d_in[7];
    float* out = (float*)d_out;

    const int n = in_sizes[0] / 3;   // 262144
    const size_t need = (size_t)32 * (size_t)n * sizeof(float);   // 33.6 MB

    if (ws_size >= need) {
        const int nb2 = (n + 511) / 512;           // 512 points per block
        enc_kernel<<<nb2 * 8, 256, 0, stream>>>(coords, emb, (float*)d_ws, n);
        const int nb = (n + 255) / 256;
        mlp_kernel<<<nb, 256, 0, stream>>>((const float*)d_ws,
                                           W0, b0, W1, b1, W2, b2, out, n);
    } else {
        const int nb = (n + 255) / 256;
        fused_kernel<<<nb, 256, 0, stream>>>(coords, emb,
                                             W0, b0, W1, b1, W2, b2, out, n);
    }
}